// Round 1
// baseline (249.505 us; speedup 1.0000x reference)
//
#include <hip/hip_runtime.h>

// FeedForwardQuantum: out = (q(x@w1^T + b1)) @ w2^T + b2
// Quantum layer reduced analytically (Clifford circuit):
//   c_i = cos(h_i)
//   q0=c0, q1=c1, q2=c0c2, q3=c1c3, q4=c0c2c4, q5=c1c3c5,
//   q6=c0c2c4c6, q7=c0c1c2c3c4c5c6c7

constexpr int THREADS        = 256;
constexpr int ROWS_PER_ITER  = 8;
constexpr int ITERS          = 4;
constexpr int ROWS_PER_BLOCK = ROWS_PER_ITER * ITERS;  // 32
constexpr int E              = 1024;
constexpr int R_TOTAL        = 8 * 4096;               // 32768 rows

__global__ __launch_bounds__(THREADS)
void ffq_kernel(const float* __restrict__ x,
                const float* __restrict__ w1,
                const float* __restrict__ b1,
                const float* __restrict__ w2,
                const float* __restrict__ b2,
                float* __restrict__ out)
{
    // [parity][row-slot][wave][f]
    __shared__ __align__(16) float part[2][ROWS_PER_ITER][4][8];
    __shared__ __align__(16) float qsh[2][ROWS_PER_ITER][8];
    __shared__ float b1s[8];

    const int t    = threadIdx.x;
    const int lane = t & 63;
    const int wid  = t >> 6;
    const int c0   = t * 4;            // this thread's 4 columns

    if (t < 8) b1s[t] = b1[t];

    // w1 slice: w1[f][c0..c0+3] in registers (8 x float4)
    float4 w1r[8];
#pragma unroll
    for (int f = 0; f < 8; ++f)
        w1r[f] = *(const float4*)(w1 + f * E + c0);

    // w2 slice: w2[c0+j][f] -> w2a[j][f]
    float w2a[4][8];
#pragma unroll
    for (int j = 0; j < 4; ++j) {
        const float4 lo = *(const float4*)(w2 + (size_t)(c0 + j) * 8);
        const float4 hi = *(const float4*)(w2 + (size_t)(c0 + j) * 8 + 4);
        w2a[j][0] = lo.x; w2a[j][1] = lo.y; w2a[j][2] = lo.z; w2a[j][3] = lo.w;
        w2a[j][4] = hi.x; w2a[j][5] = hi.y; w2a[j][6] = hi.z; w2a[j][7] = hi.w;
    }
    const float4 b2v = *(const float4*)(b2 + c0);

    const int row0 = blockIdx.x * ROWS_PER_BLOCK;

    // preload first iteration's x rows
    float4 xv[ROWS_PER_ITER];
#pragma unroll
    for (int s = 0; s < ROWS_PER_ITER; ++s)
        xv[s] = *(const float4*)(x + (size_t)(row0 + s) * E + c0);

    for (int it = 0; it < ITERS; ++it) {
        const int p        = it & 1;
        const int rbase    = row0 + it * ROWS_PER_ITER;
        const bool hasNext = (it + 1 < ITERS);

        // ---- phase 1: per-row partial dot + wave butterfly reduction ----
#pragma unroll
        for (int s = 0; s < ROWS_PER_ITER; ++s) {
            const float4 xc = xv[s];
            if (hasNext)   // prefetch next iteration's row (in flight across barriers)
                xv[s] = *(const float4*)(x + (size_t)(rbase + ROWS_PER_ITER + s) * E + c0);

            float h[8];
#pragma unroll
            for (int f = 0; f < 8; ++f)
                h[f] = xc.x * w1r[f].x + xc.y * w1r[f].y
                     + xc.z * w1r[f].z + xc.w * w1r[f].w;

            // multi-value butterfly: 8 sums across 64 lanes in 6 xor steps.
            // After step 3 lane L holds f = bitrev3(L&7); steps 4-6 all-reduce.
            {   const bool hb = lane & 1;
                float s0 = hb ? h[0] : h[4];
                float s1 = hb ? h[1] : h[5];
                float s2 = hb ? h[2] : h[6];
                float s3 = hb ? h[3] : h[7];
                s0 = __shfl_xor(s0, 1); s1 = __shfl_xor(s1, 1);
                s2 = __shfl_xor(s2, 1); s3 = __shfl_xor(s3, 1);
                h[0] = (hb ? h[4] : h[0]) + s0;
                h[1] = (hb ? h[5] : h[1]) + s1;
                h[2] = (hb ? h[6] : h[2]) + s2;
                h[3] = (hb ? h[7] : h[3]) + s3;
            }
            {   const bool hb = lane & 2;
                float s0 = hb ? h[0] : h[2];
                float s1 = hb ? h[1] : h[3];
                s0 = __shfl_xor(s0, 2); s1 = __shfl_xor(s1, 2);
                h[0] = (hb ? h[2] : h[0]) + s0;
                h[1] = (hb ? h[3] : h[1]) + s1;
            }
            float v;
            {   const bool hb = lane & 4;
                float s0 = hb ? h[0] : h[1];
                s0 = __shfl_xor(s0, 4);
                v = (hb ? h[1] : h[0]) + s0;
            }
            v += __shfl_xor(v, 8);
            v += __shfl_xor(v, 16);
            v += __shfl_xor(v, 32);

            if (lane < 8) {
                const int f = ((lane & 1) << 2) | (lane & 2) | ((lane >> 2) & 1);
                part[p][s][wid][f] = v;
            }
        }
        __syncthreads();

        // ---- phase 2: finish reduction, cos, quantum products (8 threads) ----
        if (t < ROWS_PER_ITER) {
            float hq[8];
#pragma unroll
            for (int f = 0; f < 8; ++f)
                hq[f] = part[p][t][0][f] + part[p][t][1][f]
                      + part[p][t][2][f] + part[p][t][3][f] + b1s[f];
            float c[8];
#pragma unroll
            for (int f = 0; f < 8; ++f) c[f] = __cosf(hq[f]);
            const float e1 = c[0],      o1 = c[1];
            const float e2 = e1 * c[2], o2 = o1 * c[3];
            const float e3 = e2 * c[4], o3 = o2 * c[5];
            const float e4 = e3 * c[6];
            float* qp = qsh[p][t];
            qp[0] = e1; qp[1] = o1; qp[2] = e2; qp[3] = o2;
            qp[4] = e3; qp[5] = o3; qp[6] = e4; qp[7] = e4 * o3 * c[7];
        }
        __syncthreads();

        // ---- phase 3: out = q @ w2^T + b2 ----
#pragma unroll
        for (int s = 0; s < ROWS_PER_ITER; ++s) {
            const float4 qlo = *(const float4*)(&qsh[p][s][0]);
            const float4 qhi = *(const float4*)(&qsh[p][s][4]);
            const float qv[8] = {qlo.x, qlo.y, qlo.z, qlo.w,
                                 qhi.x, qhi.y, qhi.z, qhi.w};
            float4 o = b2v;
#pragma unroll
            for (int f = 0; f < 8; ++f) {
                o.x += qv[f] * w2a[0][f];
                o.y += qv[f] * w2a[1][f];
                o.z += qv[f] * w2a[2][f];
                o.w += qv[f] * w2a[3][f];
            }
            *(float4*)(out + (size_t)(rbase + s) * E + c0) = o;
        }
    }
}

extern "C" void kernel_launch(void* const* d_in, const int* in_sizes, int n_in,
                              void* d_out, int out_size, void* d_ws, size_t ws_size,
                              hipStream_t stream)
{
    const float* x  = (const float*)d_in[0];
    const float* w1 = (const float*)d_in[1];
    const float* b1 = (const float*)d_in[2];
    const float* w2 = (const float*)d_in[3];
    const float* b2 = (const float*)d_in[4];
    float* out = (float*)d_out;

    dim3 grid(R_TOTAL / ROWS_PER_BLOCK);  // 1024 blocks
    ffq_kernel<<<grid, THREADS, 0, stream>>>(x, w1, b1, w2, b2, out);
}